// Round 4
// baseline (208.352 us; speedup 1.0000x reference)
//
#include <hip/hip_runtime.h>
#include <hip/hip_bf16.h>

// Problem: out[b,j,k] = squash_j( s[b,j,k] ), s = sum_{i<2048,u<16} W[i,j,k,u] x[b,u,i]
// GEMM view: C[m=b(32), n=(j,k)(1024)] = A[m,(i,u)] B[(i,u),n], K=32768.
// W[i][j][k][u] strides (floats): i:16384, j:1024, k:16, u:1
// x[b][u][i]    strides (floats): b:32768, u:2048, i:1

#define B_SZ   32
#define IC     2048
#define NJ     16
#define NK     64
#define SOUT   (B_SZ*NJ*NK)      // 32768
#define KSTEPS 1024              // K-steps; each covers kdim=32 = (2 i's x 16 u)
#define KSPLIT 128               // K-splits across grid.y
#define SPW    (KSTEPS/KSPLIT)   // 8 steps per wave

typedef float v4f __attribute__((ext_vector_type(4)));
typedef short v8s __attribute__((ext_vector_type(8)));
typedef unsigned int v4u __attribute__((ext_vector_type(4)));

// f32 -> bf16 round-to-nearest-even (used once in xprep)
static __device__ inline ushort f2bf(float f) {
    uint32_t u = __float_as_uint(f);
    u += 0x7FFFu + ((u >> 16) & 1u);
    return (ushort)(u >> 16);
}

// hot-loop pack: two f32 -> packed bf16 pair (round-half-up + v_perm_b32)
static __device__ inline uint packbf(float f0, float f1) {
    uint u0 = __float_as_uint(f0) + 0x8000u;
    uint u1 = __float_as_uint(f1) + 0x8000u;
    return __builtin_amdgcn_perm(u1, u0, 0x07060302u);  // [bf(f1)|bf(f0)]
}

// ---------------------------------------------------------------------------
// xprep: build A-fragments in bf16.
// kk = q*8 + jj -> i_off = kk>>4, u = kk&15 within a step (2 i's x 16 u).
// A-layout (16x16x32): lane holds A[m = lane&15][kk = (lane>>4)*8 + jj].
// xb flat: [step(1024)][mt(2)][lane(64)][jj(8)] bf16.
// ---------------------------------------------------------------------------
__global__ __launch_bounds__(256)
void caps_xprep(const float* __restrict__ x, ushort* __restrict__ xb) {
    int gid  = blockIdx.x * 256 + threadIdx.x;   // 131072 threads
    int lane = gid & 63;
    int mt   = (gid >> 6) & 1;
    int step = gid >> 7;
    int q    = lane >> 4;
    int b    = mt * 16 + (lane & 15);
    int i    = 2 * step + (q >> 1);
    int u0   = (q & 1) * 8;

    const float* xp = x + (size_t)b * (16 * IC) + (size_t)u0 * IC + i;
    ushort tmp[8];
    #pragma unroll
    for (int jj = 0; jj < 8; ++jj)
        tmp[jj] = f2bf(xp[(size_t)jj * IC]);
    *(v8s*)(xb + (size_t)gid * 8) = *(const v8s*)tmp;
}

// ---------------------------------------------------------------------------
// main: block = (j, split), 256 thr = 4 waves; wave wv = k'-tile (16 k's).
// Depth-2 register prefetch: step s+1's 4 loads issue before step s's MFMAs.
// No LDS, no barriers. Each W element read exactly once device-wide.
// ---------------------------------------------------------------------------
__global__ __launch_bounds__(256, 6)
void caps_mfma(const ushort* __restrict__ xb, const float* __restrict__ W,
               float* __restrict__ part) {
    const int tid   = threadIdx.x;
    const int wv    = tid >> 6;       // k'-tile 0..3
    const int lane  = tid & 63;
    const int j     = blockIdx.x;     // 0..15
    const int split = blockIdx.y;     // 0..KSPLIT-1
    const int n     = lane & 15;
    const int q     = lane >> 4;
    const int step0 = split * SPW;

    v4f acc0 = {0.f, 0.f, 0.f, 0.f};
    v4f acc1 = {0.f, 0.f, 0.f, 0.f};

    const float*  wp = W + (size_t)(2 * step0 + (q >> 1)) * 16384
                         + (size_t)j * 1024 + (size_t)(wv * 16 + n) * 16 + (q & 1) * 8;
    const ushort* xp = xb + (size_t)step0 * 1024 + (size_t)lane * 8;

    // prologue: load step 0
    float4 w0 = *(const float4*)(wp);
    float4 w1 = *(const float4*)(wp + 4);
    v8s    a0 = *(const v8s*)(xp);
    v8s    a1 = *(const v8s*)(xp + 512);

    #pragma unroll
    for (int s = 0; s < SPW - 1; ++s) {
        wp += 2 * 16384;
        xp += 1024;
        // prefetch step s+1 (issues before the dependent pack/MFMA below)
        float4 nw0 = *(const float4*)(wp);
        float4 nw1 = *(const float4*)(wp + 4);
        v8s    na0 = *(const v8s*)(xp);
        v8s    na1 = *(const v8s*)(xp + 512);

        v4u pk;
        pk.x = packbf(w0.x, w0.y); pk.y = packbf(w0.z, w0.w);
        pk.z = packbf(w1.x, w1.y); pk.w = packbf(w1.z, w1.w);
        v8s bb = *(v8s*)&pk;
        acc0 = __builtin_amdgcn_mfma_f32_16x16x32_bf16(a0, bb, acc0, 0, 0, 0);
        acc1 = __builtin_amdgcn_mfma_f32_16x16x32_bf16(a1, bb, acc1, 0, 0, 0);

        w0 = nw0; w1 = nw1; a0 = na0; a1 = na1;
    }
    {   // epilogue: last step
        v4u pk;
        pk.x = packbf(w0.x, w0.y); pk.y = packbf(w0.z, w0.w);
        pk.z = packbf(w1.x, w1.y); pk.w = packbf(w1.z, w1.w);
        v8s bb = *(v8s*)&pk;
        acc0 = __builtin_amdgcn_mfma_f32_16x16x32_bf16(a0, bb, acc0, 0, 0, 0);
        acc1 = __builtin_amdgcn_mfma_f32_16x16x32_bf16(a1, bb, acc1, 0, 0, 0);
    }

    // C/D layout: col = lane&15 = n (k'), row = q*4 + reg = m (b).
    float* pp = part + (size_t)split * SOUT + (size_t)j * NK + wv * 16 + n;
    #pragma unroll
    for (int r = 0; r < 4; ++r) {
        int m = q * 4 + r;
        pp[(size_t)m * 1024]        = acc0[r];
        pp[(size_t)(m + 16) * 1024] = acc1[r];
    }
}

// ---------------------------------------------------------------------------
// finish: sum K-splits, then squash over j (num_units axis, per torch source).
// 128 blocks = (b:32, k-chunk:4); 256 thr = (j:16, kc:16).
// ---------------------------------------------------------------------------
__global__ __launch_bounds__(256)
void caps_finish(const float* __restrict__ part, float* __restrict__ out) {
    __shared__ float ls[256];
    const int blk = blockIdx.x;
    const int b   = blk >> 2;
    const int k0  = (blk & 3) * 16;
    const int t   = threadIdx.x;
    const int jj  = t >> 4;
    const int kc  = t & 15;
    const size_t idx = (size_t)b * 1024 + (size_t)jj * NK + k0 + kc;

    float s = 0.0f;
    #pragma unroll 8
    for (int sp = 0; sp < KSPLIT; ++sp)
        s += part[(size_t)sp * SOUT + idx];
    ls[t] = s;
    __syncthreads();

    float msq = 0.0f;
    #pragma unroll
    for (int j2 = 0; j2 < NJ; ++j2) {
        float v = ls[j2 * 16 + kc];
        msq += v * v;
    }
    float mag = sqrtf(msq);
    out[idx] = s * (mag / (1.0f + msq));
}

extern "C" void kernel_launch(void* const* d_in, const int* in_sizes, int n_in,
                              void* d_out, int out_size, void* d_ws, size_t ws_size,
                              hipStream_t stream) {
    const float* x = (const float*)d_in[0];   // (32, 16, 2048) f32
    const float* W = (const float*)d_in[1];   // (1, 2048, 16, 64, 16) f32
    float* out  = (float*)d_out;              // (32, 16, 64) f32

    float*  part = (float*)d_ws;                            // 16 MB
    ushort* xb   = (ushort*)(part + (size_t)KSPLIT * SOUT); // + 2 MB

    caps_xprep <<<512,               256, 0, stream>>>(x, xb);
    caps_mfma  <<<dim3(16, KSPLIT),  256, 0, stream>>>(xb, W, part);
    caps_finish<<<128,               256, 0, stream>>>(part, out);
}

// Round 5
// 205.630 us; speedup vs baseline: 1.0132x; 1.0132x over previous
//
#include <hip/hip_runtime.h>
#include <hip/hip_bf16.h>

// Problem: out[b,j,k] = squash_j( s[b,j,k] ), s = sum_{i<2048,u<16} W[i,j,k,u] x[b,u,i]
// GEMM view: C[m=b(32), n=(j,k)(1024)] = A[m,(i,u)] B[(i,u),n], K=32768.
// W[i][j][k][u] strides (floats): i:16384, j:1024, k:16, u:1
// x[b][u][i]    strides (floats): b:32768, u:2048, i:1

#define B_SZ   32
#define IC     2048
#define NJ     16
#define NK     64
#define SOUT   (B_SZ*NJ*NK)      // 32768
#define KSTEPS 1024              // K-steps; each covers kdim=32 = (2 i's x 16 u)
#define KSPLIT 64                // K-splits across grid.y
#define SPW    (KSTEPS/KSPLIT)   // 16 steps per block
#define BATCH  4                 // steps per load-burst

typedef float v4f __attribute__((ext_vector_type(4)));
typedef short v8s __attribute__((ext_vector_type(8)));
typedef unsigned int v4u __attribute__((ext_vector_type(4)));

// f32 -> bf16 round-to-nearest-even (used once in xprep)
static __device__ inline ushort f2bf(float f) {
    uint32_t u = __float_as_uint(f);
    u += 0x7FFFu + ((u >> 16) & 1u);
    return (ushort)(u >> 16);
}

// hot-loop pack: two f32 -> packed bf16 pair (round-half-up + v_perm_b32)
static __device__ inline uint packbf(float f0, float f1) {
    uint u0 = __float_as_uint(f0) + 0x8000u;
    uint u1 = __float_as_uint(f1) + 0x8000u;
    return __builtin_amdgcn_perm(u1, u0, 0x07060302u);  // [bf(f1)|bf(f0)]
}

// ---------------------------------------------------------------------------
// xprep: build A-fragments in bf16.
// kk = q*8 + jj -> i_off = kk>>4, u = kk&15 within a step (2 i's x 16 u).
// A-layout (16x16x32): lane holds A[m = lane&15][kk = (lane>>4)*8 + jj].
// xb flat: [step(1024)][mt(2)][lane(64)][jj(8)] bf16.
// ---------------------------------------------------------------------------
__global__ __launch_bounds__(256)
void caps_xprep(const float* __restrict__ x, ushort* __restrict__ xb) {
    int gid  = blockIdx.x * 256 + threadIdx.x;   // 131072 threads
    int lane = gid & 63;
    int mt   = (gid >> 6) & 1;
    int step = gid >> 7;
    int q    = lane >> 4;
    int b    = mt * 16 + (lane & 15);
    int i    = 2 * step + (q >> 1);
    int u0   = (q & 1) * 8;

    const float* xp = x + (size_t)b * (16 * IC) + (size_t)u0 * IC + i;
    ushort tmp[8];
    #pragma unroll
    for (int jj = 0; jj < 8; ++jj)
        tmp[jj] = f2bf(xp[(size_t)jj * IC]);
    *(v8s*)(xb + (size_t)gid * 8) = *(const v8s*)tmp;
}

// ---------------------------------------------------------------------------
// main: block = (j, split), 256 thr = 4 waves; wave wv = k'-tile (16 k's).
// Load-burst structure: BATCH(4) steps' loads (8 W float4 + 8 xb v8s) issue
// into DISTINCT registers before any consumer -> >=16 KB in flight per wave
// even under pessimal scheduling. Outer loop unroll 1 keeps the bursts.
// No LDS, no barriers. Each W element read exactly once device-wide.
// ---------------------------------------------------------------------------
__global__ __launch_bounds__(256)
void caps_mfma(const ushort* __restrict__ xb, const float* __restrict__ W,
               float* __restrict__ part) {
    const int tid   = threadIdx.x;
    const int wv    = tid >> 6;       // k'-tile 0..3
    const int lane  = tid & 63;
    const int j     = blockIdx.x;     // 0..15
    const int split = blockIdx.y;     // 0..KSPLIT-1
    const int n     = lane & 15;
    const int q     = lane >> 4;
    const int step0 = split * SPW;

    v4f acc0 = {0.f, 0.f, 0.f, 0.f};
    v4f acc1 = {0.f, 0.f, 0.f, 0.f};

    const float*  wp = W + (size_t)(2 * step0 + (q >> 1)) * 16384
                         + (size_t)j * 1024 + (size_t)(wv * 16 + n) * 16 + (q & 1) * 8;
    const ushort* xp = xb + (size_t)step0 * 1024 + (size_t)lane * 8;

    #pragma unroll 1
    for (int ss = 0; ss < SPW / BATCH; ++ss) {
        // --- burst: issue all 16 loads into distinct regs ---
        float4 wb0[BATCH], wb1[BATCH];
        v8s    ab0[BATCH], ab1[BATCH];
        #pragma unroll
        for (int t = 0; t < BATCH; ++t) {
            const float*  wpt = wp + (size_t)t * (2 * 16384);
            const ushort* xpt = xp + (size_t)t * 1024;
            wb0[t] = *(const float4*)(wpt);
            wb1[t] = *(const float4*)(wpt + 4);
            ab0[t] = *(const v8s*)(xpt);
            ab1[t] = *(const v8s*)(xpt + 512);
        }
        // --- consume ---
        #pragma unroll
        for (int t = 0; t < BATCH; ++t) {
            v4u pk;
            pk.x = packbf(wb0[t].x, wb0[t].y); pk.y = packbf(wb0[t].z, wb0[t].w);
            pk.z = packbf(wb1[t].x, wb1[t].y); pk.w = packbf(wb1[t].z, wb1[t].w);
            v8s bb = *(v8s*)&pk;
            acc0 = __builtin_amdgcn_mfma_f32_16x16x32_bf16(ab0[t], bb, acc0, 0, 0, 0);
            acc1 = __builtin_amdgcn_mfma_f32_16x16x32_bf16(ab1[t], bb, acc1, 0, 0, 0);
        }
        wp += (size_t)BATCH * 2 * 16384;
        xp += (size_t)BATCH * 1024;
    }

    // C/D layout: col = lane&15 = n (k'), row = q*4 + reg = m (b).
    float* pp = part + (size_t)split * SOUT + (size_t)j * NK + wv * 16 + n;
    #pragma unroll
    for (int r = 0; r < 4; ++r) {
        int m = q * 4 + r;
        pp[(size_t)m * 1024]        = acc0[r];
        pp[(size_t)(m + 16) * 1024] = acc1[r];
    }
}

// ---------------------------------------------------------------------------
// finish: sum K-splits, then squash over j (num_units axis, per torch source).
// 128 blocks = (b:32, k-chunk:4); 256 thr = (j:16, kc:16).
// ---------------------------------------------------------------------------
__global__ __launch_bounds__(256)
void caps_finish(const float* __restrict__ part, float* __restrict__ out) {
    __shared__ float ls[256];
    const int blk = blockIdx.x;
    const int b   = blk >> 2;
    const int k0  = (blk & 3) * 16;
    const int t   = threadIdx.x;
    const int jj  = t >> 4;
    const int kc  = t & 15;
    const size_t idx = (size_t)b * 1024 + (size_t)jj * NK + k0 + kc;

    float s = 0.0f;
    #pragma unroll 8
    for (int sp = 0; sp < KSPLIT; ++sp)
        s += part[(size_t)sp * SOUT + idx];
    ls[t] = s;
    __syncthreads();

    float msq = 0.0f;
    #pragma unroll
    for (int j2 = 0; j2 < NJ; ++j2) {
        float v = ls[j2 * 16 + kc];
        msq += v * v;
    }
    float mag = sqrtf(msq);
    out[idx] = s * (mag / (1.0f + msq));
}

extern "C" void kernel_launch(void* const* d_in, const int* in_sizes, int n_in,
                              void* d_out, int out_size, void* d_ws, size_t ws_size,
                              hipStream_t stream) {
    const float* x = (const float*)d_in[0];   // (32, 16, 2048) f32
    const float* W = (const float*)d_in[1];   // (1, 2048, 16, 64, 16) f32
    float* out  = (float*)d_out;              // (32, 16, 64) f32

    float*  part = (float*)d_ws;                            // 8 MB
    ushort* xb   = (ushort*)(part + (size_t)KSPLIT * SOUT); // + 2 MB

    caps_xprep <<<512,               256, 0, stream>>>(x, xb);
    caps_mfma  <<<dim3(16, KSPLIT),  256, 0, stream>>>(xb, W, part);
    caps_finish<<<128,               256, 0, stream>>>(part, out);
}